// Round 2
// baseline (48.110 us; speedup 1.0000x reference)
//
#include <hip/hip_runtime.h>

// WaveletLoss: loss = sum over subbands of mean(|subband(sr) - subband(gt)|).
// Haar DWT is linear => work directly on e = sr - gt per 2x2 block:
//   contribution = |a+b+c+d| + |a+b-c-d| + |a-b+c-d| + |a-b-c+d|
//   loss = total_sum * 0.5 / (B*C*(H/2)*(W/2))
//
// Shapes: [8,3,1024,1024] f32. 24 planes of 1024x1024.
// Unit = 2 rows x 4 cols (two float4 loads per image) = two 2x2 blocks.
// Units: 24 planes * 512 row-pairs * 256 col-quads = 3,145,728.
// Single kernel: per-block partial -> one atomicAdd to d_out (fp32 ordering
// noise ~1e-7 << 2.6e-2 threshold). d_out zeroed via hipMemsetAsync each call.

#define UNITS_TOTAL (24 * 512 * 256)
#define NBLOCKS 2048
#define NTHREADS 256
#define STRIDE (NBLOCKS * NTHREADS)
#define UPT (UNITS_TOTAL / STRIDE)  // = 6, exact
// scale = 0.5 / (8*3*512*512)
#define LOSS_SCALE (0.5f / 6291456.0f)

__global__ __launch_bounds__(NTHREADS) void wl_kernel(
    const float* __restrict__ sr, const float* __restrict__ gt,
    float* __restrict__ out) {
  int tid = blockIdx.x * NTHREADS + threadIdx.x;

  float acc = 0.0f;
#pragma unroll 2
  for (int i = 0; i < UPT; ++i) {
    int u = tid + i * STRIDE;
    int p = u >> 17;            // plane = u / (512*256)
    int rem = u & 131071;       // u % (512*256)
    int rp = rem >> 8;          // row-pair index
    int cq = rem & 255;         // col-quad index
    size_t base = (size_t)p * (1024 * 1024) + (size_t)(2 * rp) * 1024 + (size_t)cq * 4;

    float4 st = *reinterpret_cast<const float4*>(sr + base);          // top row
    float4 sb = *reinterpret_cast<const float4*>(sr + base + 1024);   // bottom row
    float4 ht = *reinterpret_cast<const float4*>(gt + base);
    float4 hb = *reinterpret_cast<const float4*>(gt + base + 1024);

    float t0 = st.x - ht.x, t1 = st.y - ht.y, t2 = st.z - ht.z, t3 = st.w - ht.w;
    float b0 = sb.x - hb.x, b1 = sb.y - hb.y, b2 = sb.z - hb.z, b3 = sb.w - hb.w;

    // block 0: (t0,t1,b0,b1) — butterfly shared across the 4 abs terms
    float tp = t0 + t1, tm = t0 - t1;
    float bp = b0 + b1, bm = b0 - b1;
    acc += fabsf(tp + bp) + fabsf(tp - bp) + fabsf(tm + bm) + fabsf(tm - bm);
    // block 1: (t2,t3,b2,b3)
    float up = t2 + t3, um = t2 - t3;
    float vp = b2 + b3, vm = b2 - b3;
    acc += fabsf(up + vp) + fabsf(up - vp) + fabsf(um + vm) + fabsf(um - vm);
  }

  // wave-64 butterfly reduce
  for (int off = 32; off > 0; off >>= 1)
    acc += __shfl_down(acc, off, 64);

  __shared__ float lds[NTHREADS / 64];
  int lane = threadIdx.x & 63;
  int wave = threadIdx.x >> 6;
  if (lane == 0) lds[wave] = acc;
  __syncthreads();
  if (threadIdx.x == 0) {
    float s = lds[0] + lds[1] + lds[2] + lds[3];
    atomicAdd(out, s * LOSS_SCALE);  // device-scope by default on gfx950
  }
}

extern "C" void kernel_launch(void* const* d_in, const int* in_sizes, int n_in,
                              void* d_out, int out_size, void* d_ws, size_t ws_size,
                              hipStream_t stream) {
  const float* sr = (const float*)d_in[0];
  const float* gt = (const float*)d_in[1];
  float* out = (float*)d_out;

  hipMemsetAsync(out, 0, sizeof(float), stream);
  wl_kernel<<<NBLOCKS, NTHREADS, 0, stream>>>(sr, gt, out);
}

// Round 3
// 35.913 us; speedup vs baseline: 1.3396x; 1.3396x over previous
//
#include <hip/hip_runtime.h>

// WaveletLoss: loss = sum over subbands of mean(|subband(sr) - subband(gt)|).
// Haar DWT is linear => work directly on e = sr - gt per 2x2 block:
//   contribution = |a+b+c+d| + |a+b-c-d| + |a-b+c-d| + |a-b-c+d|
//   loss = total_sum * 0.5 / (B*C*(H/2)*(W/2))
//
// Shapes: [8,3,1024,1024] f32. 24 planes of 1024x1024.
// Unit = 2 rows x 4 cols (two float4 loads per image) = two 2x2 blocks.
// Units: 24 planes * 512 row-pairs * 256 col-quads = 3,145,728.
//
// Round-2 lesson: 2048 same-address atomicAdds cost ~+12us (serialized tail +
// memset dispatch). Two-kernel partial/reduce is faster; keep reduce to one
// 64-lane wave (float4 loads, shuffle-only) to minimize the tail.

#define UNITS_TOTAL (24 * 512 * 256)
#define NBLOCKS 2048
#define NTHREADS 256
// scale = 0.5 / (8*3*512*512)
#define LOSS_SCALE (0.5f / 6291456.0f)

__global__ __launch_bounds__(NTHREADS) void wl_partial_kernel(
    const float* __restrict__ sr, const float* __restrict__ gt,
    float* __restrict__ partials) {
  int tid = blockIdx.x * blockDim.x + threadIdx.x;
  int stride = gridDim.x * blockDim.x;

  float acc = 0.0f;
  for (int u = tid; u < UNITS_TOTAL; u += stride) {
    int p = u >> 17;            // plane = u / (512*256)
    int rem = u & 131071;       // u % (512*256)
    int rp = rem >> 8;          // row-pair index
    int cq = rem & 255;         // col-quad index
    size_t base = (size_t)p * (1024 * 1024) + (size_t)(2 * rp) * 1024 + (size_t)cq * 4;

    float4 st = *reinterpret_cast<const float4*>(sr + base);          // top row
    float4 sb = *reinterpret_cast<const float4*>(sr + base + 1024);   // bottom row
    float4 ht = *reinterpret_cast<const float4*>(gt + base);
    float4 hb = *reinterpret_cast<const float4*>(gt + base + 1024);

    float t0 = st.x - ht.x, t1 = st.y - ht.y, t2 = st.z - ht.z, t3 = st.w - ht.w;
    float b0 = sb.x - hb.x, b1 = sb.y - hb.y, b2 = sb.z - hb.z, b3 = sb.w - hb.w;

    // block 0: (t0,t1,b0,b1) — butterfly shared across the 4 abs terms
    float tp = t0 + t1, tm = t0 - t1;
    float bp = b0 + b1, bm = b0 - b1;
    acc += fabsf(tp + bp) + fabsf(tp - bp) + fabsf(tm + bm) + fabsf(tm - bm);
    // block 1: (t2,t3,b2,b3)
    float up = t2 + t3, um = t2 - t3;
    float vp = b2 + b3, vm = b2 - b3;
    acc += fabsf(up + vp) + fabsf(up - vp) + fabsf(um + vm) + fabsf(um - vm);
  }

  // wave-64 butterfly reduce
  for (int off = 32; off > 0; off >>= 1)
    acc += __shfl_down(acc, off, 64);

  __shared__ float lds[NTHREADS / 64];
  int lane = threadIdx.x & 63;
  int wave = threadIdx.x >> 6;
  if (lane == 0) lds[wave] = acc;
  __syncthreads();
  if (threadIdx.x == 0) {
    float s = lds[0] + lds[1] + lds[2] + lds[3];
    partials[blockIdx.x] = s * LOSS_SCALE;
  }
}

// Single-wave reduce: 64 lanes x 8 float4 = 2048 floats, shuffle-only.
__global__ __launch_bounds__(64) void wl_reduce_kernel(
    const float* __restrict__ partials, float* __restrict__ out) {
  const float4* p4 = reinterpret_cast<const float4*>(partials);
  float acc = 0.0f;
#pragma unroll
  for (int i = 0; i < 8; ++i) {
    float4 v = p4[threadIdx.x + i * 64];
    acc += (v.x + v.y) + (v.z + v.w);
  }
  for (int off = 32; off > 0; off >>= 1)
    acc += __shfl_down(acc, off, 64);
  if (threadIdx.x == 0) out[0] = acc;
}

extern "C" void kernel_launch(void* const* d_in, const int* in_sizes, int n_in,
                              void* d_out, int out_size, void* d_ws, size_t ws_size,
                              hipStream_t stream) {
  const float* sr = (const float*)d_in[0];
  const float* gt = (const float*)d_in[1];
  float* partials = (float*)d_ws;  // needs NBLOCKS*4 = 8 KiB of scratch

  wl_partial_kernel<<<NBLOCKS, NTHREADS, 0, stream>>>(sr, gt, partials);
  wl_reduce_kernel<<<1, 64, 0, stream>>>(partials, (float*)d_out);
}